// Round 2
// baseline (4055.698 us; speedup 1.0000x reference)
//
#include <hip/hip_runtime.h>
#include <math.h>

static constexpr int BATCH = 4;
static constexpr int CIN   = 256;
static constexpr int CKEY  = 448;
static constexpr int NTOK  = 4096;   // 64*64 spatial tokens

// ---------------------------------------------------------------------------
// proj_nt: out[b][n][o] = sum_k X[b][k][n] * W[o][k] + bias[o]   (token-major)
// grid: (NTOK/64, O/64, BATCH), block 256
// ---------------------------------------------------------------------------
template<int K>
__global__ __launch_bounds__(256)
void proj_nt(const float* __restrict__ X, const float* __restrict__ W,
             const float* __restrict__ bias, float* __restrict__ out, int O)
{
    const int n0 = blockIdx.x * 64;
    const int o0 = blockIdx.y * 64;
    const int b  = blockIdx.z;
    const int t  = threadIdx.x;
    const int tx = t & 15, ty = t >> 4;   // ty -> 4 n rows, tx -> 4 o cols

    __shared__ float Xs[16][68];   // [k][n]
    __shared__ float Wst[16][68];  // [k][o]  (W transposed chunk)

    const float* Xb = X + (size_t)b * K * NTOK;
    float acc[4][4] = {};

    for (int kc = 0; kc < K; kc += 16) {
        {   // Xs[k][n] <- X[b][kc+k][n0+n], coalesced along n
            const int k = t >> 4, n4 = (t & 15) * 4;
            *(float4*)&Xs[k][n4] =
                *(const float4*)(Xb + (size_t)(kc + k) * NTOK + n0 + n4);
        }
        {   // Wst[k][o] <- W[o0+o][kc+k] (transpose in LDS)
            const int o = t >> 2, k4 = (t & 3) * 4;
            const float4 v = *(const float4*)(W + (size_t)(o0 + o) * K + kc + k4);
            Wst[k4 + 0][o] = v.x; Wst[k4 + 1][o] = v.y;
            Wst[k4 + 2][o] = v.z; Wst[k4 + 3][o] = v.w;
        }
        __syncthreads();
        #pragma unroll
        for (int k = 0; k < 16; ++k) {
            float a[4];
            #pragma unroll
            for (int i = 0; i < 4; ++i) a[i] = Xs[k][4 * ty + i];
            const float4 bb = *(const float4*)&Wst[k][4 * tx];
            const float bv[4] = {bb.x, bb.y, bb.z, bb.w};
            #pragma unroll
            for (int i = 0; i < 4; ++i)
                #pragma unroll
                for (int j = 0; j < 4; ++j) acc[i][j] += a[i] * bv[j];
        }
        __syncthreads();
    }
    #pragma unroll
    for (int i = 0; i < 4; ++i) {
        const int n = n0 + 4 * ty + i;
        float4 v;
        v.x = acc[i][0] + bias[o0 + 4 * tx + 0];
        v.y = acc[i][1] + bias[o0 + 4 * tx + 1];
        v.z = acc[i][2] + bias[o0 + 4 * tx + 2];
        v.w = acc[i][3] + bias[o0 + 4 * tx + 3];
        *(float4*)(out + ((size_t)b * NTOK + n) * O + o0 + 4 * tx) = v;
    }
}

// ---------------------------------------------------------------------------
// proj_tn: out[b][o][m] = sum_k W[o][k] * X[b][k][m] + bias[o]  (chan-major)
// grid: (NTOK/64, O/64, BATCH), block 256
// ---------------------------------------------------------------------------
template<int K>
__global__ __launch_bounds__(256)
void proj_tn(const float* __restrict__ X, const float* __restrict__ W,
             const float* __restrict__ bias, float* __restrict__ out)
{
    const int m0 = blockIdx.x * 64;
    const int o0 = blockIdx.y * 64;
    const int b  = blockIdx.z;
    const int t  = threadIdx.x;
    const int tx = t & 15, ty = t >> 4;   // ty -> 4 o rows, tx -> 4 m cols

    __shared__ float Wo[64][20];   // [o][k]
    __shared__ float Xs[16][68];   // [k][m]

    const float* Xb = X + (size_t)b * K * NTOK;
    float acc[4][4] = {};

    for (int kc = 0; kc < K; kc += 16) {
        {   // Wo[o][k]
            const int o = t >> 2, k4 = (t & 3) * 4;
            *(float4*)&Wo[o][k4] =
                *(const float4*)(W + (size_t)(o0 + o) * K + kc + k4);
        }
        {   // Xs[k][m]
            const int k = t >> 4, m4 = (t & 15) * 4;
            *(float4*)&Xs[k][m4] =
                *(const float4*)(Xb + (size_t)(kc + k) * NTOK + m0 + m4);
        }
        __syncthreads();
        #pragma unroll
        for (int k = 0; k < 16; ++k) {
            float a[4];
            #pragma unroll
            for (int i = 0; i < 4; ++i) a[i] = Wo[4 * ty + i][k];
            const float4 bb = *(const float4*)&Xs[k][4 * tx];
            const float bv[4] = {bb.x, bb.y, bb.z, bb.w};
            #pragma unroll
            for (int i = 0; i < 4; ++i)
                #pragma unroll
                for (int j = 0; j < 4; ++j) acc[i][j] += a[i] * bv[j];
        }
        __syncthreads();
    }
    #pragma unroll
    for (int i = 0; i < 4; ++i) {
        const int o = o0 + 4 * ty + i;
        const float bo = bias[o];
        float4 v;
        v.x = acc[i][0] + bo; v.y = acc[i][1] + bo;
        v.z = acc[i][2] + bo; v.w = acc[i][3] + bo;
        *(float4*)(out + ((size_t)b * CKEY + o) * NTOK + m0 + 4 * tx) = v;
    }
}

// ---------------------------------------------------------------------------
// content stats: per (b,c) mean + 1/sqrt(unbiased var + eps) over 4096 tokens
// ---------------------------------------------------------------------------
__global__ __launch_bounds__(256)
void content_stats(const float* __restrict__ content, float* __restrict__ stat)
{
    const int bc = blockIdx.x;
    const float* p = content + (size_t)bc * NTOK;
    float s = 0.f, s2 = 0.f;
    for (int i = threadIdx.x; i < NTOK; i += 256) {
        const float x = p[i];
        s += x; s2 += x * x;
    }
    #pragma unroll
    for (int off = 32; off; off >>= 1) {
        s  += __shfl_down(s, off);
        s2 += __shfl_down(s2, off);
    }
    __shared__ float rs[4], rs2[4];
    const int w = threadIdx.x >> 6;
    if ((threadIdx.x & 63) == 0) { rs[w] = s; rs2[w] = s2; }
    __syncthreads();
    if (threadIdx.x == 0) {
        const float S  = rs[0] + rs[1] + rs[2] + rs[3];
        const float S2 = rs2[0] + rs2[1] + rs2[2] + rs2[3];
        const float mean = S / (float)NTOK;
        const float var  = (S2 - S * mean) / (float)(NTOK - 1);
        stat[bc] = mean;
        stat[BATCH * CIN + bc] = rsqrtf(var + 1e-5f);
    }
}

// ---------------------------------------------------------------------------
// fused flash attention + weighted mean/std + AdaAttN epilogue
// block: 256 threads, 32 query rows; m-tiles of 64
// grid: BATCH * (NTOK/32)
// ---------------------------------------------------------------------------
__global__ __launch_bounds__(256)
void attn_fused(const float* __restrict__ Q, const float* __restrict__ G,
                const float* __restrict__ Hv, const int* __restrict__ cmask,
                const int* __restrict__ smask, const float* __restrict__ content,
                const float* __restrict__ stat, float* __restrict__ out)
{
    const int b  = blockIdx.x >> 7;            // 128 row-tiles per batch
    const int n0 = (blockIdx.x & 127) * 32;
    const int t  = threadIdx.x;
    const int tx = t & 15, ty = t >> 4;        // ty -> 2 rows; tx -> 4 S-cols / 16 PV-cols

    __shared__ float Qs[32][452];   // query tile [n][ck], padded
    __shared__ float Hs[64][256];   // value tile [m][c]
    __shared__ float Ps[32][68];    // exp(S) tile [n][m], padded
    __shared__ float Gs[64][68];    // key chunk  [k][m], padded

    {   // stage Q tile once: 32 rows x 448
        const float* Qb = Q + ((size_t)b * NTOK + n0) * CKEY;
        #pragma unroll
        for (int it = 0; it < 14; ++it) {
            const int idx = it * 256 + t;
            const int r = idx / 112, o4 = (idx % 112) * 4;
            *(float4*)&Qs[r][o4] = *(const float4*)(Qb + (size_t)r * CKEY + o4);
        }
    }
    const int cmv[2] = { cmask[b * NTOK + n0 + 2 * ty] != 0,
                         cmask[b * NTOK + n0 + 2 * ty + 1] != 0 };

    float macc[2][16] = {};
    float sacc[2][16] = {};
    float lacc[2] = {};

    __syncthreads();

    for (int m0 = 0; m0 < NTOK; m0 += 64) {
        // ---- S tile: [32 n] x [64 m], K = 448 in chunks of 64 ----
        float s[2][4] = {};
        for (int kc = 0; kc < CKEY; kc += 64) {
            #pragma unroll
            for (int it = 0; it < 4; ++it) {
                const int idx = it * 256 + t;
                const int k = idx >> 4, m4 = (idx & 15) * 4;
                *(float4*)&Gs[k][m4] =
                    *(const float4*)(G + ((size_t)b * CKEY + kc + k) * NTOK + m0 + m4);
            }
            __syncthreads();
            #pragma unroll
            for (int k = 0; k < 64; k += 4) {
                float a[2][4], g[4][4];
                *(float4*)a[0] = *(const float4*)&Qs[2 * ty    ][kc + k];
                *(float4*)a[1] = *(const float4*)&Qs[2 * ty + 1][kc + k];
                *(float4*)g[0] = *(const float4*)&Gs[k + 0][4 * tx];
                *(float4*)g[1] = *(const float4*)&Gs[k + 1][4 * tx];
                *(float4*)g[2] = *(const float4*)&Gs[k + 2][4 * tx];
                *(float4*)g[3] = *(const float4*)&Gs[k + 3][4 * tx];
                #pragma unroll
                for (int i = 0; i < 2; ++i)
                    #pragma unroll
                    for (int kk = 0; kk < 4; ++kk)
                        #pragma unroll
                        for (int j = 0; j < 4; ++j)
                            s[i][j] += a[i][kk] * g[kk][j];
            }
            __syncthreads();
        }
        // ---- mask + exp (no max-sub: logits are small by construction) ----
        {
            const int4 sm = *(const int4*)(smask + (size_t)b * NTOK + m0 + 4 * tx);
            const int smv[4] = { sm.x, sm.y, sm.z, sm.w };
            #pragma unroll
            for (int i = 0; i < 2; ++i)
                #pragma unroll
                for (int j = 0; j < 4; ++j) {
                    const float p = (cmv[i] && smv[j] == 0)
                                        ? 0.0f
                                        : __expf(fminf(s[i][j], 60.0f));
                    Ps[2 * ty + i][4 * tx + j] = p;
                }
        }
        // ---- stage Hv tile (safe: all threads passed the k-loop barriers) ----
        #pragma unroll
        for (int pp = 0; pp < 16; ++pp) {
            const int m = pp * 4 + (t >> 6);
            const int c4 = (t & 63) * 4;
            *(float4*)&Hs[m][c4] =
                *(const float4*)(Hv + ((size_t)b * NTOK + m0 + m) * CIN + c4);
        }
        __syncthreads();
        // ---- PV: accumulate sum(p), sum(p*h), sum(p*h^2) ----
        #pragma unroll 4
        for (int m = 0; m < 64; ++m) {
            const float p0 = Ps[2 * ty][m];
            const float p1 = Ps[2 * ty + 1][m];
            lacc[0] += p0; lacc[1] += p1;
            #pragma unroll
            for (int jj = 0; jj < 4; ++jj) {
                const float4 h = *(const float4*)&Hs[m][64 * jj + 4 * tx];
                const float hv[4] = { h.x, h.y, h.z, h.w };
                #pragma unroll
                for (int j = 0; j < 4; ++j) {
                    const float h2 = hv[j] * hv[j];
                    macc[0][4 * jj + j] += p0 * hv[j];
                    macc[1][4 * jj + j] += p1 * hv[j];
                    sacc[0][4 * jj + j] += p0 * h2;
                    sacc[1][4 * jj + j] += p1 * h2;
                }
            }
        }
        __syncthreads();
    }

    // ---- epilogue: mean/std + std*mvn(content)+mean, direct to out ----
    #pragma unroll
    for (int i = 0; i < 2; ++i) {
        const int n = n0 + 2 * ty + i;
        const float rl = 1.0f / lacc[i];
        #pragma unroll
        for (int jj = 0; jj < 4; ++jj)
            #pragma unroll
            for (int j = 0; j < 4; ++j) {
                const int c = 64 * jj + 4 * tx + j;
                const float mu = macc[i][4 * jj + j] * rl;
                const float m2 = sacc[i][4 * jj + j] * rl;
                const float sd = sqrtf(fmaxf(m2 - mu * mu, 0.0f));
                const size_t idx = ((size_t)b * CIN + c) * NTOK + n;
                const float cmn = stat[b * CIN + c];
                const float crs = stat[BATCH * CIN + b * CIN + c];
                out[idx] = sd * ((content[idx] - cmn) * crs) + mu;
            }
    }
}

// ---------------------------------------------------------------------------
extern "C" void kernel_launch(void* const* d_in, const int* in_sizes, int n_in,
                              void* d_out, int out_size, void* d_ws, size_t ws_size,
                              hipStream_t stream)
{
    const float* content = (const float*)d_in[0];
    const float* style   = (const float*)d_in[1];
    const float* ckey    = (const float*)d_in[2];
    const float* skey    = (const float*)d_in[3];
    const int*   cmask   = (const int*)d_in[4];
    const int*   smask   = (const int*)d_in[5];
    const float* Wf      = (const float*)d_in[6];
    const float* bf      = (const float*)d_in[7];
    const float* Wg      = (const float*)d_in[8];
    const float* bg      = (const float*)d_in[9];
    const float* Wh      = (const float*)d_in[10];
    const float* bh      = (const float*)d_in[11];
    float* out = (float*)d_out;

    float* Qw    = (float*)d_ws;                          // [B][N][CKEY]
    float* Gw    = Qw + (size_t)BATCH * NTOK * CKEY;      // [B][CKEY][N]
    float* Hw    = Gw + (size_t)BATCH * NTOK * CKEY;      // [B][N][CIN]
    float* statw = Hw + (size_t)BATCH * NTOK * CIN;       // mean[1024], rstd[1024]

    proj_nt<CKEY><<<dim3(NTOK / 64, CKEY / 64, BATCH), 256, 0, stream>>>(
        ckey, Wf, bf, Qw, CKEY);
    proj_tn<CKEY><<<dim3(NTOK / 64, CKEY / 64, BATCH), 256, 0, stream>>>(
        skey, Wg, bg, Gw);
    proj_nt<CIN><<<dim3(NTOK / 64, CIN / 64, BATCH), 256, 0, stream>>>(
        style, Wh, bh, Hw, CIN);
    content_stats<<<BATCH * CIN, 256, 0, stream>>>(content, statw);
    attn_fused<<<BATCH * (NTOK / 32), 256, 0, stream>>>(
        Qw, Gw, Hw, cmask, smask, content, statw, out);
}

// Round 4
// 2137.935 us; speedup vs baseline: 1.8970x; 1.8970x over previous
//
#include <hip/hip_runtime.h>
#include <math.h>

typedef unsigned short u16;
typedef __attribute__((ext_vector_type(8))) short short8;
typedef __attribute__((ext_vector_type(4))) float f32x4;

static constexpr int BATCH = 4;
static constexpr int CIN   = 256;
static constexpr int CKEY  = 448;
static constexpr int NTOK  = 4096;

// ---- bf16 helpers (round-to-nearest-even) ---------------------------------
__device__ __forceinline__ u16 f2bf(float x) {
    unsigned u = __float_as_uint(x);
    return (u16)((u + 0x7fffu + ((u >> 16) & 1u)) >> 16);
}
__device__ __forceinline__ float bf2f(u16 h) {
    return __uint_as_float(((unsigned)h) << 16);
}

// LDS layout: per panel [rows][BK=32] bf16, stored as 16B slots (4 slots/row).
// Pair-interleaved XOR mapping -> 2-way bank conflicts (free) on frag reads,
// bijective within each 8-slot pair-block.  Returns 16B-slot index.
__device__ __forceinline__ int lds16(int row, int s) {
    return ((row >> 1) << 3) + ((((row & 1) << 2) + s) ^ ((row >> 1) & 7));
}

// ---------------------------------------------------------------------------
// proj_nt_split: out[b][n][o] = sum_k X[b][k][n]*W[o][k] + bias[o], split bf16
// ---------------------------------------------------------------------------
template<int K, bool SPLIT>
__global__ __launch_bounds__(256)
void proj_nt_split(const float* __restrict__ X, const float* __restrict__ W,
                   const float* __restrict__ bias,
                   u16* __restrict__ outH, u16* __restrict__ outL, int O)
{
    const int n0 = blockIdx.x * 64;
    const int o0 = blockIdx.y * 64;
    const int b  = blockIdx.z;
    const int t  = threadIdx.x;
    const int tx = t & 15, ty = t >> 4;

    __shared__ float Xs[16][68];
    __shared__ float Wst[16][68];

    const float* Xb = X + (size_t)b * K * NTOK;
    float acc[4][4] = {};

    for (int kc = 0; kc < K; kc += 16) {
        {
            const int k = t >> 4, n4 = (t & 15) * 4;
            *(float4*)&Xs[k][n4] =
                *(const float4*)(Xb + (size_t)(kc + k) * NTOK + n0 + n4);
        }
        {
            const int o = t >> 2, k4 = (t & 3) * 4;
            const float4 v = *(const float4*)(W + (size_t)(o0 + o) * K + kc + k4);
            Wst[k4 + 0][o] = v.x; Wst[k4 + 1][o] = v.y;
            Wst[k4 + 2][o] = v.z; Wst[k4 + 3][o] = v.w;
        }
        __syncthreads();
        #pragma unroll
        for (int k = 0; k < 16; ++k) {
            float a[4];
            #pragma unroll
            for (int i = 0; i < 4; ++i) a[i] = Xs[k][4 * ty + i];
            const float4 bb = *(const float4*)&Wst[k][4 * tx];
            const float bv[4] = {bb.x, bb.y, bb.z, bb.w};
            #pragma unroll
            for (int i = 0; i < 4; ++i)
                #pragma unroll
                for (int j = 0; j < 4; ++j) acc[i][j] += a[i] * bv[j];
        }
        __syncthreads();
    }
    #pragma unroll
    for (int i = 0; i < 4; ++i) {
        const int n = n0 + 4 * ty + i;
        u16 h[4], l[4];
        #pragma unroll
        for (int j = 0; j < 4; ++j) {
            const float v = acc[i][j] + bias[o0 + 4 * tx + j];
            h[j] = f2bf(v);
            l[j] = SPLIT ? f2bf(v - bf2f(h[j])) : (u16)0;
        }
        const size_t oidx = ((size_t)b * NTOK + n) * O + o0 + 4 * tx;
        *(ushort4*)(outH + oidx) = make_ushort4(h[0], h[1], h[2], h[3]);
        if (SPLIT)
            *(ushort4*)(outL + oidx) = make_ushort4(l[0], l[1], l[2], l[3]);
    }
}

// ---------------------------------------------------------------------------
// proj_tn_split (for H): out[b][o][m] = W·X + b, writes H and H^2, split bf16
// ---------------------------------------------------------------------------
template<int K, bool SPLIT>
__global__ __launch_bounds__(256)
void proj_tn_split(const float* __restrict__ X, const float* __restrict__ W,
                   const float* __restrict__ bias,
                   u16* __restrict__ Hh, u16* __restrict__ Hl,
                   u16* __restrict__ H2h, u16* __restrict__ H2l)
{
    const int m0 = blockIdx.x * 64;
    const int o0 = blockIdx.y * 64;
    const int b  = blockIdx.z;
    const int t  = threadIdx.x;
    const int tx = t & 15, ty = t >> 4;

    __shared__ float Wo[64][20];
    __shared__ float Xs[16][68];

    const float* Xb = X + (size_t)b * K * NTOK;
    float acc[4][4] = {};

    for (int kc = 0; kc < K; kc += 16) {
        {
            const int o = t >> 2, k4 = (t & 3) * 4;
            *(float4*)&Wo[o][k4] =
                *(const float4*)(W + (size_t)(o0 + o) * K + kc + k4);
        }
        {
            const int k = t >> 4, m4 = (t & 15) * 4;
            *(float4*)&Xs[k][m4] =
                *(const float4*)(Xb + (size_t)(kc + k) * NTOK + m0 + m4);
        }
        __syncthreads();
        #pragma unroll
        for (int k = 0; k < 16; ++k) {
            float a[4];
            #pragma unroll
            for (int i = 0; i < 4; ++i) a[i] = Wo[4 * ty + i][k];
            const float4 bb = *(const float4*)&Xs[k][4 * tx];
            const float bv[4] = {bb.x, bb.y, bb.z, bb.w};
            #pragma unroll
            for (int i = 0; i < 4; ++i)
                #pragma unroll
                for (int j = 0; j < 4; ++j) acc[i][j] += a[i] * bv[j];
        }
        __syncthreads();
    }
    #pragma unroll
    for (int i = 0; i < 4; ++i) {
        const int o = o0 + 4 * ty + i;
        const float bo = bias[o];
        u16 vh[4], vl[4], wh[4], wl[4];
        #pragma unroll
        for (int j = 0; j < 4; ++j) {
            const float v  = acc[i][j] + bo;
            const float v2 = v * v;
            vh[j] = f2bf(v);
            wh[j] = f2bf(v2);
            vl[j] = SPLIT ? f2bf(v  - bf2f(vh[j])) : (u16)0;
            wl[j] = SPLIT ? f2bf(v2 - bf2f(wh[j])) : (u16)0;
        }
        const size_t oidx = ((size_t)b * CIN + o) * NTOK + m0 + 4 * tx;
        *(ushort4*)(Hh  + oidx) = make_ushort4(vh[0], vh[1], vh[2], vh[3]);
        *(ushort4*)(H2h + oidx) = make_ushort4(wh[0], wh[1], wh[2], wh[3]);
        if (SPLIT) {
            *(ushort4*)(Hl  + oidx) = make_ushort4(vl[0], vl[1], vl[2], vl[3]);
            *(ushort4*)(H2l + oidx) = make_ushort4(wl[0], wl[1], wl[2], wl[3]);
        }
    }
}

// ---------------------------------------------------------------------------
// content stats: per (b,c) mean + rstd (unbiased) over 4096 tokens
// ---------------------------------------------------------------------------
__global__ __launch_bounds__(256)
void content_stats(const float* __restrict__ content, float* __restrict__ stat)
{
    const int bc = blockIdx.x;
    const float* p = content + (size_t)bc * NTOK;
    float s = 0.f, s2 = 0.f;
    for (int i = threadIdx.x; i < NTOK; i += 256) {
        const float x = p[i];
        s += x; s2 += x * x;
    }
    #pragma unroll
    for (int off = 32; off; off >>= 1) {
        s  += __shfl_down(s, off);
        s2 += __shfl_down(s2, off);
    }
    __shared__ float rs[4], rs2[4];
    const int w = threadIdx.x >> 6;
    if ((threadIdx.x & 63) == 0) { rs[w] = s; rs2[w] = s2; }
    __syncthreads();
    if (threadIdx.x == 0) {
        const float S  = rs[0] + rs[1] + rs[2] + rs[3];
        const float S2 = rs2[0] + rs2[1] + rs2[2] + rs2[3];
        const float mean = S / (float)NTOK;
        const float var  = (S2 - S * mean) / (float)(NTOK - 1);
        stat[bc] = mean;
        stat[BATCH * CIN + bc] = rsqrtf(var + 1e-5f);
    }
}

__global__ void zero_f32(float* p, int n)
{
    const int i = blockIdx.x * 256 + threadIdx.x;
    if (i < n) p[i] = 0.f;
}

// ---------------------------------------------------------------------------
// s_gemm: S = Q·G^T (split-bf16 when SA) -> p = mask?0:exp(S) -> Ph/Pl,
// row sums into lacc (atomics).  Tile 128x128, BK=32, 4 waves.
// grid: (NTOK/128 m-tiles, R/128 n-tiles, BATCH)
// ---------------------------------------------------------------------------
template<bool SA>
__global__ __launch_bounds__(256)
void s_gemm(const u16* __restrict__ Qh, const u16* __restrict__ Ql,
            const u16* __restrict__ Gh, const u16* __restrict__ Gl,
            const int* __restrict__ cmask, const int* __restrict__ smask,
            float* __restrict__ lacc,
            u16* __restrict__ Ph, u16* __restrict__ Pl, int n_base, int Rrows)
{
    const int m0 = blockIdx.x * 128;
    const int nl_base = blockIdx.y * 128;        // local (chunk) row base
    const int n0 = n_base + nl_base;             // global row base
    const int b  = blockIdx.z;
    const int t  = threadIdx.x;
    const int lane = t & 63, wid = t >> 6;
    const int g = lane >> 4, lr = lane & 15;
    const int wrow = (wid & 1) * 64;             // n side within tile
    const int wcol = (wid >> 1) * 64;            // m side within tile

    __shared__ __align__(16) u16 LAh[4096], LAl[4096], LBh[4096], LBl[4096];

    const size_t qoff = ((size_t)b * NTOK + n0) * CKEY;
    const size_t goff = ((size_t)b * NTOK + m0) * CKEY;

    const f32x4 zf = {0.f, 0.f, 0.f, 0.f};
    f32x4 acc[4][4];
    #pragma unroll
    for (int i = 0; i < 4; ++i)
        #pragma unroll
        for (int j = 0; j < 4; ++j) acc[i][j] = zf;

    uint4 rg[8];
#define LOADA(kc) do {                                                        \
    const size_t o_ = (size_t)(t >> 2) * CKEY + (kc) + (t & 3) * 8;           \
    rg[0] = *(const uint4*)(Qh + qoff + o_);                                  \
    rg[1] = *(const uint4*)(Qh + qoff + o_ + (size_t)64 * CKEY);              \
    rg[4] = *(const uint4*)(Gh + goff + o_);                                  \
    rg[5] = *(const uint4*)(Gh + goff + o_ + (size_t)64 * CKEY);              \
    if (SA) {                                                                 \
        rg[2] = *(const uint4*)(Ql + qoff + o_);                              \
        rg[3] = *(const uint4*)(Ql + qoff + o_ + (size_t)64 * CKEY);          \
        rg[6] = *(const uint4*)(Gl + goff + o_);                              \
        rg[7] = *(const uint4*)(Gl + goff + o_ + (size_t)64 * CKEY);          \
    }                                                                         \
} while (0)

    LOADA(0);
    for (int kc = 0; kc < CKEY; kc += 32) {
        __syncthreads();
        {
            const int r0 = t >> 2, s0 = t & 3;
            const int sl0 = lds16(r0, s0) * 8, sl1 = lds16(r0 + 64, s0) * 8;
            *(uint4*)&LAh[sl0] = rg[0]; *(uint4*)&LAh[sl1] = rg[1];
            *(uint4*)&LBh[sl0] = rg[4]; *(uint4*)&LBh[sl1] = rg[5];
            if (SA) {
                *(uint4*)&LAl[sl0] = rg[2]; *(uint4*)&LAl[sl1] = rg[3];
                *(uint4*)&LBl[sl0] = rg[6]; *(uint4*)&LBl[sl1] = rg[7];
            }
        }
        __syncthreads();
        if (kc + 32 < CKEY) { LOADA(kc + 32); }   // prefetch under MFMA

        short8 bh[4], bl[4];
        #pragma unroll
        for (int tc = 0; tc < 4; ++tc) {
            const int br = wcol + tc * 16 + lr;
            bh[tc] = *(const short8*)&LBh[lds16(br, g) * 8];
            if (SA) bl[tc] = *(const short8*)&LBl[lds16(br, g) * 8];
        }
        #pragma unroll
        for (int tr = 0; tr < 4; ++tr) {
            const int ar = wrow + tr * 16 + lr;
            const short8 ah = *(const short8*)&LAh[lds16(ar, g) * 8];
            short8 al;
            if (SA) al = *(const short8*)&LAl[lds16(ar, g) * 8];
            #pragma unroll
            for (int tc = 0; tc < 4; ++tc) {
                acc[tr][tc] = __builtin_amdgcn_mfma_f32_16x16x32_bf16(ah, bh[tc], acc[tr][tc], 0, 0, 0);
                if (SA) {
                    acc[tr][tc] = __builtin_amdgcn_mfma_f32_16x16x32_bf16(ah, bl[tc], acc[tr][tc], 0, 0, 0);
                    acc[tr][tc] = __builtin_amdgcn_mfma_f32_16x16x32_bf16(al, bh[tc], acc[tr][tc], 0, 0, 0);
                }
            }
        }
    }
#undef LOADA

    // epilogue: mask + exp + split-store + row sums
    int smv[4];
    #pragma unroll
    for (int tc = 0; tc < 4; ++tc)
        smv[tc] = smask[b * NTOK + m0 + wcol + tc * 16 + lr];

    #pragma unroll
    for (int tr = 0; tr < 4; ++tr) {
        int cmr[4];
        #pragma unroll
        for (int r = 0; r < 4; ++r)
            cmr[r] = cmask[b * NTOK + n0 + wrow + tr * 16 + 4 * g + r];
        float rowsum[4] = {0.f, 0.f, 0.f, 0.f};
        #pragma unroll
        for (int tc = 0; tc < 4; ++tc) {
            #pragma unroll
            for (int r = 0; r < 4; ++r) {
                const float p = (cmr[r] && smv[tc] == 0) ? 0.f
                                                         : __expf(acc[tr][tc][r]);
                rowsum[r] += p;
                const u16 hi = f2bf(p);
                const u16 lo = f2bf(p - bf2f(hi));
                const int nloc = nl_base + wrow + tr * 16 + 4 * g + r;
                const int m = m0 + wcol + tc * 16 + lr;
                const size_t pidx = ((size_t)b * Rrows + nloc) * NTOK + m;
                Ph[pidx] = hi; Pl[pidx] = lo;
            }
        }
        #pragma unroll
        for (int r = 0; r < 4; ++r) {
            float v = rowsum[r];
            v += __shfl_xor(v, 1); v += __shfl_xor(v, 2);
            v += __shfl_xor(v, 4); v += __shfl_xor(v, 8);
            if (lr == 0)
                atomicAdd(&lacc[b * NTOK + n0 + wrow + tr * 16 + 4 * g + r], v);
        }
    }
}

// ---------------------------------------------------------------------------
// pv_gemm: mean/m2 = (P·H, P·H2)/lacc + AdaAttN epilogue.  C-tile [c][n],
// tile 128c x 64n, K = NTOK, BK=32.  grid: (R/64 n-tiles, 2 c-tiles, BATCH)
// ---------------------------------------------------------------------------
template<bool SH>
__global__ __launch_bounds__(256)
void pv_gemm(const u16* __restrict__ Hh, const u16* __restrict__ Hl,
             const u16* __restrict__ H2h, const u16* __restrict__ H2l,
             const u16* __restrict__ Ph, const u16* __restrict__ Pl,
             const float* __restrict__ lacc, const float* __restrict__ content,
             const float* __restrict__ cstat, float* __restrict__ out,
             int n_base, int Rrows)
{
    const int nl0 = blockIdx.x * 64;            // local n window
    const int c0  = blockIdx.y * 128;
    const int b   = blockIdx.z;
    const int t = threadIdx.x, lane = t & 63, wid = t >> 6;
    const int g = lane >> 4, lr = lane & 15;
    const int wrow = (wid & 1) * 64;            // c side
    const int wcol = (wid >> 1) * 32;           // n side

    __shared__ __align__(16) u16 LHh[4096], LHl[4096], L2h[4096], L2l[4096];
    __shared__ __align__(16) u16 LPh[2048], LPl[2048];

    const size_t hoff = ((size_t)b * CIN + c0) * NTOK;
    const size_t poff = ((size_t)b * Rrows + nl0) * NTOK;

    const f32x4 zf = {0.f, 0.f, 0.f, 0.f};
    f32x4 accM[4][2], accS[4][2];
    #pragma unroll
    for (int i = 0; i < 4; ++i)
        #pragma unroll
        for (int j = 0; j < 2; ++j) { accM[i][j] = zf; accS[i][j] = zf; }

    uint4 ra[8], rb[2];
#define LOADC(kc) do {                                                          \
    const size_t oA = (size_t)(t >> 2) * NTOK + (kc) + (t & 3) * 8;             \
    ra[0] = *(const uint4*)(Hh  + hoff + oA);                                   \
    ra[1] = *(const uint4*)(Hh  + hoff + oA + (size_t)64 * NTOK);               \
    ra[4] = *(const uint4*)(H2h + hoff + oA);                                   \
    ra[5] = *(const uint4*)(H2h + hoff + oA + (size_t)64 * NTOK);               \
    if (SH) {                                                                   \
        ra[2] = *(const uint4*)(Hl  + hoff + oA);                               \
        ra[3] = *(const uint4*)(Hl  + hoff + oA + (size_t)64 * NTOK);           \
        ra[6] = *(const uint4*)(H2l + hoff + oA);                               \
        ra[7] = *(const uint4*)(H2l + hoff + oA + (size_t)64 * NTOK);           \
    }                                                                           \
    rb[0] = *(const uint4*)(Ph  + poff + oA);                                   \
    rb[1] = *(const uint4*)(Pl  + poff + oA);                                   \
} while (0)

    LOADC(0);
    for (int kc = 0; kc < NTOK; kc += 32) {
        __syncthreads();
        {
            const int r0 = t >> 2, s0 = t & 3;
            const int sl0 = lds16(r0, s0) * 8, sl1 = lds16(r0 + 64, s0) * 8;
            *(uint4*)&LHh[sl0] = ra[0]; *(uint4*)&LHh[sl1] = ra[1];
            *(uint4*)&L2h[sl0] = ra[4]; *(uint4*)&L2h[sl1] = ra[5];
            if (SH) {
                *(uint4*)&LHl[sl0] = ra[2]; *(uint4*)&LHl[sl1] = ra[3];
                *(uint4*)&L2l[sl0] = ra[6]; *(uint4*)&L2l[sl1] = ra[7];
            }
            *(uint4*)&LPh[sl0] = rb[0];
            *(uint4*)&LPl[sl0] = rb[1];
        }
        __syncthreads();
        if (kc + 32 < NTOK) { LOADC(kc + 32); }   // prefetch under MFMA

        short8 pbh[2], pbl[2];
        #pragma unroll
        for (int tc = 0; tc < 2; ++tc) {
            const int pr = wcol + tc * 16 + lr;
            pbh[tc] = *(const short8*)&LPh[lds16(pr, g) * 8];
            pbl[tc] = *(const short8*)&LPl[lds16(pr, g) * 8];
        }
        #pragma unroll
        for (int tr = 0; tr < 4; ++tr) {
            const int cr = wrow + tr * 16 + lr;
            const short8 hh  = *(const short8*)&LHh[lds16(cr, g) * 8];
            const short8 q2h = *(const short8*)&L2h[lds16(cr, g) * 8];
            short8 hl, q2l;
            if (SH) {
                hl  = *(const short8*)&LHl[lds16(cr, g) * 8];
                q2l = *(const short8*)&L2l[lds16(cr, g) * 8];
            }
            #pragma unroll
            for (int tc = 0; tc < 2; ++tc) {
                accM[tr][tc] = __builtin_amdgcn_mfma_f32_16x16x32_bf16(hh,  pbh[tc], accM[tr][tc], 0, 0, 0);
                accM[tr][tc] = __builtin_amdgcn_mfma_f32_16x16x32_bf16(hh,  pbl[tc], accM[tr][tc], 0, 0, 0);
                accS[tr][tc] = __builtin_amdgcn_mfma_f32_16x16x32_bf16(q2h, pbh[tc], accS[tr][tc], 0, 0, 0);
                accS[tr][tc] = __builtin_amdgcn_mfma_f32_16x16x32_bf16(q2h, pbl[tc], accS[tr][tc], 0, 0, 0);
                if (SH) {
                    accM[tr][tc] = __builtin_amdgcn_mfma_f32_16x16x32_bf16(hl,  pbh[tc], accM[tr][tc], 0, 0, 0);
                    accS[tr][tc] = __builtin_amdgcn_mfma_f32_16x16x32_bf16(q2l, pbh[tc], accS[tr][tc], 0, 0, 0);
                }
            }
        }
    }
#undef LOADC

    // epilogue: normalize, std, AdaAttN transform, store
    #pragma unroll
    for (int tc = 0; tc < 2; ++tc) {
        const int n = n_base + nl0 + wcol + tc * 16 + lr;
        const float rl = 1.f / fmaxf(lacc[b * NTOK + n], 1e-35f);
        #pragma unroll
        for (int tr = 0; tr < 4; ++tr) {
            #pragma unroll
            for (int r = 0; r < 4; ++r) {
                const int c = c0 + wrow + tr * 16 + 4 * g + r;
                const float mu = accM[tr][tc][r] * rl;
                const float m2 = accS[tr][tc][r] * rl;
                const float sd = sqrtf(fmaxf(m2 - mu * mu, 0.f));
                const size_t oidx = ((size_t)b * CIN + c) * NTOK + n;
                const float cm = cstat[b * CIN + c];
                const float cr = cstat[BATCH * CIN + b * CIN + c];
                out[oidx] = sd * ((content[oidx] - cm) * cr) + mu;
            }
        }
    }
}

// ---------------------------------------------------------------------------
extern "C" void kernel_launch(void* const* d_in, const int* in_sizes, int n_in,
                              void* d_out, int out_size, void* d_ws, size_t ws_size,
                              hipStream_t stream)
{
    const float* content = (const float*)d_in[0];
    const float* style   = (const float*)d_in[1];
    const float* ckey    = (const float*)d_in[2];
    const float* skey    = (const float*)d_in[3];
    const int*   cmask   = (const int*)d_in[4];
    const int*   smask   = (const int*)d_in[5];
    const float* Wf      = (const float*)d_in[6];
    const float* bf      = (const float*)d_in[7];
    const float* Wg      = (const float*)d_in[8];
    const float* bg      = (const float*)d_in[9];
    const float* Wh      = (const float*)d_in[10];
    const float* bh      = (const float*)d_in[11];
    float* out = (float*)d_out;

    const size_t SZQ = (size_t)BATCH * NTOK * CKEY;   // elements (u16)
    const size_t SZH = (size_t)BATCH * CIN * NTOK;

    char* cur = (char*)d_ws;
    auto take = [&](size_t bytes) { char* r = cur; cur += bytes; return r; };

    // essential hi arrays + aux
    u16* Qh  = (u16*)take(SZQ * 2);
    u16* Gh  = (u16*)take(SZQ * 2);
    u16* Hh  = (u16*)take(SZH * 2);
    u16* H2h = (u16*)take(SZH * 2);
    float* laccp = (float*)take((size_t)BATCH * NTOK * 4);
    float* cstat = (float*)take((size_t)2 * BATCH * CIN * 4);

    const size_t PMIN = (size_t)128 * BATCH * NTOK * 4;   // R=128 chunk bytes
    size_t rem = ws_size - (size_t)(cur - (char*)d_ws);

    // precision tiers by available workspace
    bool SA = false, SH = false;
    u16 *Ql = Qh, *Gl = Gh, *Hl = Hh, *H2l = H2h;   // dummies (unused if !S*)
    if (rem >= 2 * SZQ * 2 + 2 * SZH * 2 + PMIN) {
        SA = true; SH = true;
        Ql  = (u16*)take(SZQ * 2);
        Gl  = (u16*)take(SZQ * 2);
        Hl  = (u16*)take(SZH * 2);
        H2l = (u16*)take(SZH * 2);
    } else if (rem >= 2 * SZQ * 2 + PMIN) {
        SA = true;
        Ql = (u16*)take(SZQ * 2);
        Gl = (u16*)take(SZQ * 2);
    }
    rem = ws_size - (size_t)(cur - (char*)d_ws);
    int R = NTOK;
    while (R > 128 && (size_t)R * BATCH * NTOK * 4 > rem) R >>= 1;
    u16* Ph = (u16*)cur;
    u16* Pl = Ph + (size_t)BATCH * R * NTOK;

    // projections
    if (SA) {
        proj_nt_split<CKEY, true><<<dim3(NTOK / 64, CKEY / 64, BATCH), 256, 0, stream>>>(
            ckey, Wf, bf, Qh, Ql, CKEY);
        proj_nt_split<CKEY, true><<<dim3(NTOK / 64, CKEY / 64, BATCH), 256, 0, stream>>>(
            skey, Wg, bg, Gh, Gl, CKEY);
    } else {
        proj_nt_split<CKEY, false><<<dim3(NTOK / 64, CKEY / 64, BATCH), 256, 0, stream>>>(
            ckey, Wf, bf, Qh, Ql, CKEY);
        proj_nt_split<CKEY, false><<<dim3(NTOK / 64, CKEY / 64, BATCH), 256, 0, stream>>>(
            skey, Wg, bg, Gh, Gl, CKEY);
    }
    if (SH)
        proj_tn_split<CIN, true><<<dim3(NTOK / 64, CIN / 64, BATCH), 256, 0, stream>>>(
            style, Wh, bh, Hh, Hl, H2h, H2l);
    else
        proj_tn_split<CIN, false><<<dim3(NTOK / 64, CIN / 64, BATCH), 256, 0, stream>>>(
            style, Wh, bh, Hh, Hl, H2h, H2l);

    content_stats<<<BATCH * CIN, 256, 0, stream>>>(content, cstat);
    zero_f32<<<(BATCH * NTOK + 255) / 256, 256, 0, stream>>>(laccp, BATCH * NTOK);

    const int npass = NTOK / R;
    for (int p = 0; p < npass; ++p) {
        if (SA)
            s_gemm<true><<<dim3(NTOK / 128, R / 128, BATCH), 256, 0, stream>>>(
                Qh, Ql, Gh, Gl, cmask, smask, laccp, Ph, Pl, p * R, R);
        else
            s_gemm<false><<<dim3(NTOK / 128, R / 128, BATCH), 256, 0, stream>>>(
                Qh, Ql, Gh, Gl, cmask, smask, laccp, Ph, Pl, p * R, R);
        if (SH)
            pv_gemm<true><<<dim3(R / 64, CIN / 128, BATCH), 256, 0, stream>>>(
                Hh, Hl, H2h, H2l, Ph, Pl, laccp, content, cstat, out, p * R, R);
        else
            pv_gemm<false><<<dim3(R / 64, CIN / 128, BATCH), 256, 0, stream>>>(
                Hh, Hl, H2h, H2l, Ph, Pl, laccp, content, cstat, out, p * R, R);
    }
}

// Round 8
// 1918.437 us; speedup vs baseline: 2.1141x; 1.1144x over previous
//
#include <hip/hip_runtime.h>
#include <math.h>

typedef unsigned short u16;
typedef __attribute__((ext_vector_type(8))) short short8;
typedef __attribute__((ext_vector_type(4))) float f32x4;

static constexpr int BATCH = 4;
static constexpr int CIN   = 256;
static constexpr int CKEY  = 448;
static constexpr int NTOK  = 4096;

// ---- bf16 helpers (round-to-nearest-even) ---------------------------------
__device__ __forceinline__ u16 f2bf(float x) {
    unsigned u = __float_as_uint(x);
    return (u16)((u + 0x7fffu + ((u >> 16) & 1u)) >> 16);
}
__device__ __forceinline__ float bf2f(u16 h) {
    return __uint_as_float(((unsigned)h) << 16);
}

// LDS layout: [rows][BK=32] bf16 panels as 16B slots (4/row), pair-interleaved
// XOR mapping -> 2-way conflicts (free), bijective.  Returns 16B-slot index.
__device__ __forceinline__ int lds16(int row, int s) {
    return ((row >> 1) << 3) + ((((row & 1) << 2) + s) ^ ((row >> 1) & 7));
}

// ---------------------------------------------------------------------------
// proj_nt_split: out[b][n][o] = sum_k X[b][k][n]*W[o][k] + bias[o], split bf16
// ---------------------------------------------------------------------------
template<int K>
__global__ __launch_bounds__(256)
void proj_nt_split(const float* __restrict__ X, const float* __restrict__ W,
                   const float* __restrict__ bias,
                   u16* __restrict__ outH, u16* __restrict__ outL, int O)
{
    const int n0 = blockIdx.x * 64;
    const int o0 = blockIdx.y * 64;
    const int b  = blockIdx.z;
    const int t  = threadIdx.x;
    const int tx = t & 15, ty = t >> 4;

    __shared__ float Xs[16][68];
    __shared__ float Wst[16][68];

    const float* Xb = X + (size_t)b * K * NTOK;
    float acc[4][4] = {};

    for (int kc = 0; kc < K; kc += 16) {
        {
            const int k = t >> 4, n4 = (t & 15) * 4;
            *(float4*)&Xs[k][n4] =
                *(const float4*)(Xb + (size_t)(kc + k) * NTOK + n0 + n4);
        }
        {
            const int o = t >> 2, k4 = (t & 3) * 4;
            const float4 v = *(const float4*)(W + (size_t)(o0 + o) * K + kc + k4);
            Wst[k4 + 0][o] = v.x; Wst[k4 + 1][o] = v.y;
            Wst[k4 + 2][o] = v.z; Wst[k4 + 3][o] = v.w;
        }
        __syncthreads();
        #pragma unroll
        for (int k = 0; k < 16; ++k) {
            float a[4];
            #pragma unroll
            for (int i = 0; i < 4; ++i) a[i] = Xs[k][4 * ty + i];
            const float4 bb = *(const float4*)&Wst[k][4 * tx];
            const float bv[4] = {bb.x, bb.y, bb.z, bb.w};
            #pragma unroll
            for (int i = 0; i < 4; ++i)
                #pragma unroll
                for (int j = 0; j < 4; ++j) acc[i][j] += a[i] * bv[j];
        }
        __syncthreads();
    }
    #pragma unroll
    for (int i = 0; i < 4; ++i) {
        const int n = n0 + 4 * ty + i;
        u16 h[4], l[4];
        #pragma unroll
        for (int j = 0; j < 4; ++j) {
            const float v = acc[i][j] + bias[o0 + 4 * tx + j];
            h[j] = f2bf(v);
            l[j] = f2bf(v - bf2f(h[j]));
        }
        const size_t oidx = ((size_t)b * NTOK + n) * O + o0 + 4 * tx;
        *(ushort4*)(outH + oidx) = make_ushort4(h[0], h[1], h[2], h[3]);
        *(ushort4*)(outL + oidx) = make_ushort4(l[0], l[1], l[2], l[3]);
    }
}

// ---------------------------------------------------------------------------
// proj_tn_split (for H): writes H (2-term) and H^2 (2-term), chan-major
// ---------------------------------------------------------------------------
template<int K>
__global__ __launch_bounds__(256)
void proj_tn_split(const float* __restrict__ X, const float* __restrict__ W,
                   const float* __restrict__ bias,
                   u16* __restrict__ Hh, u16* __restrict__ Hl,
                   u16* __restrict__ H2h, u16* __restrict__ H2l)
{
    const int m0 = blockIdx.x * 64;
    const int o0 = blockIdx.y * 64;
    const int b  = blockIdx.z;
    const int t  = threadIdx.x;
    const int tx = t & 15, ty = t >> 4;

    __shared__ float Wo[64][20];
    __shared__ float Xs[16][68];

    const float* Xb = X + (size_t)b * K * NTOK;
    float acc[4][4] = {};

    for (int kc = 0; kc < K; kc += 16) {
        {
            const int o = t >> 2, k4 = (t & 3) * 4;
            *(float4*)&Wo[o][k4] =
                *(const float4*)(W + (size_t)(o0 + o) * K + kc + k4);
        }
        {
            const int k = t >> 4, m4 = (t & 15) * 4;
            *(float4*)&Xs[k][m4] =
                *(const float4*)(Xb + (size_t)(kc + k) * NTOK + m0 + m4);
        }
        __syncthreads();
        #pragma unroll
        for (int k = 0; k < 16; ++k) {
            float a[4];
            #pragma unroll
            for (int i = 0; i < 4; ++i) a[i] = Wo[4 * ty + i][k];
            const float4 bb = *(const float4*)&Xs[k][4 * tx];
            const float bv[4] = {bb.x, bb.y, bb.z, bb.w};
            #pragma unroll
            for (int i = 0; i < 4; ++i)
                #pragma unroll
                for (int j = 0; j < 4; ++j) acc[i][j] += a[i] * bv[j];
        }
        __syncthreads();
    }
    #pragma unroll
    for (int i = 0; i < 4; ++i) {
        const int o = o0 + 4 * ty + i;
        const float bo = bias[o];
        u16 vh[4], vl[4], wh[4], wl[4];
        #pragma unroll
        for (int j = 0; j < 4; ++j) {
            const float v  = acc[i][j] + bo;
            const float v2 = v * v;
            vh[j] = f2bf(v);  vl[j] = f2bf(v  - bf2f(vh[j]));
            wh[j] = f2bf(v2); wl[j] = f2bf(v2 - bf2f(wh[j]));
        }
        const size_t oidx = ((size_t)b * CIN + o) * NTOK + m0 + 4 * tx;
        *(ushort4*)(Hh  + oidx) = make_ushort4(vh[0], vh[1], vh[2], vh[3]);
        *(ushort4*)(Hl  + oidx) = make_ushort4(vl[0], vl[1], vl[2], vl[3]);
        *(ushort4*)(H2h + oidx) = make_ushort4(wh[0], wh[1], wh[2], wh[3]);
        *(ushort4*)(H2l + oidx) = make_ushort4(wl[0], wl[1], wl[2], wl[3]);
    }
}

// ---------------------------------------------------------------------------
// content stats: per (b,c) mean + rstd (unbiased) over 4096 tokens
// ---------------------------------------------------------------------------
__global__ __launch_bounds__(256)
void content_stats(const float* __restrict__ content, float* __restrict__ stat)
{
    const int bc = blockIdx.x;
    const float* p = content + (size_t)bc * NTOK;
    float s = 0.f, s2 = 0.f;
    for (int i = threadIdx.x; i < NTOK; i += 256) {
        const float x = p[i];
        s += x; s2 += x * x;
    }
    #pragma unroll
    for (int off = 32; off; off >>= 1) {
        s  += __shfl_down(s, off);
        s2 += __shfl_down(s2, off);
    }
    __shared__ float rs[4], rs2[4];
    const int w = threadIdx.x >> 6;
    if ((threadIdx.x & 63) == 0) { rs[w] = s; rs2[w] = s2; }
    __syncthreads();
    if (threadIdx.x == 0) {
        const float S  = rs[0] + rs[1] + rs[2] + rs[3];
        const float S2 = rs2[0] + rs2[1] + rs2[2] + rs2[3];
        const float mean = S / (float)NTOK;
        const float var  = (S2 - S * mean) / (float)(NTOK - 1);
        stat[bc] = mean;
        stat[BATCH * CIN + bc] = rsqrtf(var + 1e-5f);
    }
}

__global__ void zero_f32(float* p, int n)
{
    const int i = blockIdx.x * 256 + threadIdx.x;
    if (i < n) p[i] = 0.f;
}

// ---------------------------------------------------------------------------
// s_gemm: S = Q·G^T (split-bf16 3-term) -> p = mask?0:exp(S) -> Ph/Pl,
// row sums into lacc (atomics).  Tile 128x128, BK=32, 4 waves.
// grid: (NTOK/128 m-tiles, R/128 n-tiles, BATCH)
// ---------------------------------------------------------------------------
__global__ __launch_bounds__(256)
void s_gemm(const u16* __restrict__ Qh, const u16* __restrict__ Ql,
            const u16* __restrict__ Gh, const u16* __restrict__ Gl,
            const int* __restrict__ cmask, const int* __restrict__ smask,
            float* __restrict__ lacc,
            u16* __restrict__ Ph, u16* __restrict__ Pl, int n_base, int Rrows)
{
    const int m0 = blockIdx.x * 128;
    const int nl_base = blockIdx.y * 128;
    const int n0 = n_base + nl_base;
    const int b  = blockIdx.z;
    const int t  = threadIdx.x;
    const int lane = t & 63, wid = t >> 6;
    const int g = lane >> 4, lr = lane & 15;
    const int wrow = (wid & 1) * 64;
    const int wcol = (wid >> 1) * 64;

    __shared__ __align__(16) u16 LAh[4096], LAl[4096], LBh[4096], LBl[4096];

    const size_t qoff = ((size_t)b * NTOK + n0) * CKEY;
    const size_t goff = ((size_t)b * NTOK + m0) * CKEY;

    const f32x4 zf = {0.f, 0.f, 0.f, 0.f};
    f32x4 acc[4][4];
    #pragma unroll
    for (int i = 0; i < 4; ++i)
        #pragma unroll
        for (int j = 0; j < 4; ++j) acc[i][j] = zf;

    uint4 rg[8];
#define LOADA(kc) do {                                                        \
    const size_t o_ = (size_t)(t >> 2) * CKEY + (kc) + (t & 3) * 8;           \
    rg[0] = *(const uint4*)(Qh + qoff + o_);                                  \
    rg[1] = *(const uint4*)(Qh + qoff + o_ + (size_t)64 * CKEY);              \
    rg[2] = *(const uint4*)(Ql + qoff + o_);                                  \
    rg[3] = *(const uint4*)(Ql + qoff + o_ + (size_t)64 * CKEY);              \
    rg[4] = *(const uint4*)(Gh + goff + o_);                                  \
    rg[5] = *(const uint4*)(Gh + goff + o_ + (size_t)64 * CKEY);              \
    rg[6] = *(const uint4*)(Gl + goff + o_);                                  \
    rg[7] = *(const uint4*)(Gl + goff + o_ + (size_t)64 * CKEY);              \
} while (0)

    LOADA(0);
    for (int kc = 0; kc < CKEY; kc += 32) {
        __syncthreads();
        {
            const int r0 = t >> 2, s0 = t & 3;
            const int sl0 = lds16(r0, s0) * 8, sl1 = lds16(r0 + 64, s0) * 8;
            *(uint4*)&LAh[sl0] = rg[0]; *(uint4*)&LAh[sl1] = rg[1];
            *(uint4*)&LAl[sl0] = rg[2]; *(uint4*)&LAl[sl1] = rg[3];
            *(uint4*)&LBh[sl0] = rg[4]; *(uint4*)&LBh[sl1] = rg[5];
            *(uint4*)&LBl[sl0] = rg[6]; *(uint4*)&LBl[sl1] = rg[7];
        }
        __syncthreads();
        if (kc + 32 < CKEY) { LOADA(kc + 32); }   // prefetch under MFMA

        short8 bh[4], bl[4];
        #pragma unroll
        for (int tc = 0; tc < 4; ++tc) {
            const int br = wcol + tc * 16 + lr;
            bh[tc] = *(const short8*)&LBh[lds16(br, g) * 8];
            bl[tc] = *(const short8*)&LBl[lds16(br, g) * 8];
        }
        #pragma unroll
        for (int tr = 0; tr < 4; ++tr) {
            const int ar = wrow + tr * 16 + lr;
            const short8 ah = *(const short8*)&LAh[lds16(ar, g) * 8];
            const short8 al = *(const short8*)&LAl[lds16(ar, g) * 8];
            #pragma unroll
            for (int tc = 0; tc < 4; ++tc) {
                acc[tr][tc] = __builtin_amdgcn_mfma_f32_16x16x32_bf16(ah, bh[tc], acc[tr][tc], 0, 0, 0);
                acc[tr][tc] = __builtin_amdgcn_mfma_f32_16x16x32_bf16(ah, bl[tc], acc[tr][tc], 0, 0, 0);
                acc[tr][tc] = __builtin_amdgcn_mfma_f32_16x16x32_bf16(al, bh[tc], acc[tr][tc], 0, 0, 0);
            }
        }
    }
#undef LOADA

    // epilogue: mask + exp + split-store + row sums
    int smv[4];
    #pragma unroll
    for (int tc = 0; tc < 4; ++tc)
        smv[tc] = smask[b * NTOK + m0 + wcol + tc * 16 + lr];

    #pragma unroll
    for (int tr = 0; tr < 4; ++tr) {
        int cmr[4];
        #pragma unroll
        for (int r = 0; r < 4; ++r)
            cmr[r] = cmask[b * NTOK + n0 + wrow + tr * 16 + 4 * g + r];
        float rowsum[4] = {0.f, 0.f, 0.f, 0.f};
        #pragma unroll
        for (int tc = 0; tc < 4; ++tc) {
            #pragma unroll
            for (int r = 0; r < 4; ++r) {
                const float p = (cmr[r] && smv[tc] == 0) ? 0.f
                                                         : __expf(acc[tr][tc][r]);
                rowsum[r] += p;
                const u16 hi = f2bf(p);
                const u16 lo = f2bf(p - bf2f(hi));
                const int nloc = nl_base + wrow + tr * 16 + 4 * g + r;
                const int m = m0 + wcol + tc * 16 + lr;
                const size_t pidx = ((size_t)b * Rrows + nloc) * NTOK + m;
                Ph[pidx] = hi; Pl[pidx] = lo;
            }
        }
        #pragma unroll
        for (int r = 0; r < 4; ++r) {
            float v = rowsum[r];
            v += __shfl_xor(v, 1); v += __shfl_xor(v, 2);
            v += __shfl_xor(v, 4); v += __shfl_xor(v, 8);
            if (lr == 0)
                atomicAdd(&lacc[b * NTOK + n0 + wrow + tr * 16 + 4 * g + r], v);
        }
    }
}

// ---------------------------------------------------------------------------
// pv_gemm: mean = P·H (3-term), m2 = P·H2 (3-term), /lacc, AdaAttN epilogue.
// Tile 64c x 64n, BK=32, 4 waves (each 32c x 32n).
// 1-D grid, bijective XCD swizzle: the 4 c-tiles of one n-tile share an XCD
// (P panel served from that XCD's L2).  nblocks % 8 == 0 for all R tiers.
// ---------------------------------------------------------------------------
__global__ __launch_bounds__(256)
void pv_gemm(const u16* __restrict__ Hh, const u16* __restrict__ Hl,
             const u16* __restrict__ H2h, const u16* __restrict__ H2l,
             const u16* __restrict__ Ph, const u16* __restrict__ Pl,
             const float* __restrict__ lacc, const float* __restrict__ content,
             const float* __restrict__ cstat, float* __restrict__ out,
             int n_base, int Rrows)
{
    const int nblocks = gridDim.x;
    const int cpx = nblocks >> 3;
    const int bid = blockIdx.x;
    const int swz = (bid & 7) * cpx + (bid >> 3);   // XCD-chunked remap
    const int ntiles = Rrows >> 6;
    const int c0  = (swz & 3) * 64;
    const int n_t = (swz >> 2) % ntiles;
    const int b   = swz / (4 * ntiles);
    const int nl0 = n_t * 64;

    const int t = threadIdx.x, lane = t & 63, wid = t >> 6;
    const int g = lane >> 4, lr = lane & 15;
    const int wrow = (wid & 1) * 32;            // c side
    const int wcol = (wid >> 1) * 32;           // n side

    __shared__ __align__(16) u16 LHh[2048], LHl[2048], L2h[2048], L2l[2048];
    __shared__ __align__(16) u16 LPh[2048], LPl[2048];

    const size_t hoff = ((size_t)b * CIN + c0) * NTOK;
    const size_t poff = ((size_t)b * Rrows + nl0) * NTOK;

    const f32x4 zf = {0.f, 0.f, 0.f, 0.f};
    f32x4 accM[2][2], accS[2][2];
    #pragma unroll
    for (int i = 0; i < 2; ++i)
        #pragma unroll
        for (int j = 0; j < 2; ++j) { accM[i][j] = zf; accS[i][j] = zf; }

    uint4 ra[4], rb[2];
#define LOADC(kc) do {                                                          \
    const size_t oA = (size_t)(t >> 2) * NTOK + (kc) + (t & 3) * 8;             \
    ra[0] = *(const uint4*)(Hh  + hoff + oA);                                   \
    ra[1] = *(const uint4*)(Hl  + hoff + oA);                                   \
    ra[2] = *(const uint4*)(H2h + hoff + oA);                                   \
    ra[3] = *(const uint4*)(H2l + hoff + oA);                                   \
    rb[0] = *(const uint4*)(Ph  + poff + oA);                                   \
    rb[1] = *(const uint4*)(Pl  + poff + oA);                                   \
} while (0)

    LOADC(0);
    for (int kc = 0; kc < NTOK; kc += 32) {
        __syncthreads();
        {
            const int sl0 = lds16(t >> 2, t & 3) * 8;
            *(uint4*)&LHh[sl0] = ra[0];
            *(uint4*)&LHl[sl0] = ra[1];
            *(uint4*)&L2h[sl0] = ra[2];
            *(uint4*)&L2l[sl0] = ra[3];
            *(uint4*)&LPh[sl0] = rb[0];
            *(uint4*)&LPl[sl0] = rb[1];
        }
        __syncthreads();
        if (kc + 32 < NTOK) { LOADC(kc + 32); }   // prefetch under MFMA

        short8 pbh[2], pbl[2];
        #pragma unroll
        for (int tc = 0; tc < 2; ++tc) {
            const int pr = wcol + tc * 16 + lr;
            pbh[tc] = *(const short8*)&LPh[lds16(pr, g) * 8];
            pbl[tc] = *(const short8*)&LPl[lds16(pr, g) * 8];
        }
        #pragma unroll
        for (int tr = 0; tr < 2; ++tr) {
            const int cr = wrow + tr * 16 + lr;
            const short8 hh  = *(const short8*)&LHh[lds16(cr, g) * 8];
            const short8 hl  = *(const short8*)&LHl[lds16(cr, g) * 8];
            const short8 q2h = *(const short8*)&L2h[lds16(cr, g) * 8];
            const short8 q2l = *(const short8*)&L2l[lds16(cr, g) * 8];
            #pragma unroll
            for (int tc = 0; tc < 2; ++tc) {
                accM[tr][tc] = __builtin_amdgcn_mfma_f32_16x16x32_bf16(hh,  pbh[tc], accM[tr][tc], 0, 0, 0);
                accM[tr][tc] = __builtin_amdgcn_mfma_f32_16x16x32_bf16(hh,  pbl[tc], accM[tr][tc], 0, 0, 0);
                accM[tr][tc] = __builtin_amdgcn_mfma_f32_16x16x32_bf16(hl,  pbh[tc], accM[tr][tc], 0, 0, 0);
                accS[tr][tc] = __builtin_amdgcn_mfma_f32_16x16x32_bf16(q2h, pbh[tc], accS[tr][tc], 0, 0, 0);
                accS[tr][tc] = __builtin_amdgcn_mfma_f32_16x16x32_bf16(q2h, pbl[tc], accS[tr][tc], 0, 0, 0);
                accS[tr][tc] = __builtin_amdgcn_mfma_f32_16x16x32_bf16(q2l, pbh[tc], accS[tr][tc], 0, 0, 0);
            }
        }
    }
#undef LOADC

    // epilogue: normalize, std, AdaAttN transform, store
    #pragma unroll
    for (int tc = 0; tc < 2; ++tc) {
        const int n = n_base + nl0 + wcol + tc * 16 + lr;
        const float rl = 1.f / fmaxf(lacc[b * NTOK + n], 1e-35f);
        #pragma unroll
        for (int tr = 0; tr < 2; ++tr) {
            #pragma unroll
            for (int r = 0; r < 4; ++r) {
                const int c = c0 + wrow + tr * 16 + 4 * g + r;
                const float mu = accM[tr][tc][r] * rl;
                const float m2 = accS[tr][tc][r] * rl;
                const float sd = sqrtf(fmaxf(m2 - mu * mu, 0.f));
                const size_t oidx = ((size_t)b * CIN + c) * NTOK + n;
                const float cm = cstat[b * CIN + c];
                const float cr = cstat[BATCH * CIN + b * CIN + c];
                out[oidx] = sd * ((content[oidx] - cm) * cr) + mu;
            }
        }
    }
}

// ---------------------------------------------------------------------------
extern "C" void kernel_launch(void* const* d_in, const int* in_sizes, int n_in,
                              void* d_out, int out_size, void* d_ws, size_t ws_size,
                              hipStream_t stream)
{
    const float* content = (const float*)d_in[0];
    const float* style   = (const float*)d_in[1];
    const float* ckey    = (const float*)d_in[2];
    const float* skey    = (const float*)d_in[3];
    const int*   cmask   = (const int*)d_in[4];
    const int*   smask   = (const int*)d_in[5];
    const float* Wf      = (const float*)d_in[6];
    const float* bf      = (const float*)d_in[7];
    const float* Wg      = (const float*)d_in[8];
    const float* bg      = (const float*)d_in[9];
    const float* Wh      = (const float*)d_in[10];
    const float* bh      = (const float*)d_in[11];
    float* out = (float*)d_out;

    const size_t SZQ = (size_t)BATCH * NTOK * CKEY;   // elements (u16)
    const size_t SZH = (size_t)BATCH * CIN * NTOK;

    char* cur = (char*)d_ws;
    auto take = [&](size_t bytes) { char* r = cur; cur += bytes; return r; };

    u16* Qh  = (u16*)take(SZQ * 2);
    u16* Ql  = (u16*)take(SZQ * 2);
    u16* Gh  = (u16*)take(SZQ * 2);
    u16* Gl  = (u16*)take(SZQ * 2);
    u16* Hh  = (u16*)take(SZH * 2);
    u16* Hl  = (u16*)take(SZH * 2);
    u16* H2h = (u16*)take(SZH * 2);
    u16* H2l = (u16*)take(SZH * 2);
    float* laccp = (float*)take((size_t)BATCH * NTOK * 4);
    float* cstat = (float*)take((size_t)2 * BATCH * CIN * 4);

    const size_t rem = ws_size - (size_t)(cur - (char*)d_ws);
    int R = NTOK;                                     // P 2-term: 4 B/elem
    while (R > 128 && (size_t)R * BATCH * NTOK * 4 > rem) R >>= 1;
    u16* Ph = (u16*)cur;
    u16* Pl = Ph + (size_t)BATCH * R * NTOK;

    proj_nt_split<CKEY><<<dim3(NTOK / 64, CKEY / 64, BATCH), 256, 0, stream>>>(
        ckey, Wf, bf, Qh, Ql, CKEY);
    proj_nt_split<CKEY><<<dim3(NTOK / 64, CKEY / 64, BATCH), 256, 0, stream>>>(
        skey, Wg, bg, Gh, Gl, CKEY);
    proj_tn_split<CIN><<<dim3(NTOK / 64, CIN / 64, BATCH), 256, 0, stream>>>(
        style, Wh, bh, Hh, Hl, H2h, H2l);
    content_stats<<<BATCH * CIN, 256, 0, stream>>>(content, cstat);
    zero_f32<<<(BATCH * NTOK + 255) / 256, 256, 0, stream>>>(laccp, BATCH * NTOK);

    const int npass = NTOK / R;
    for (int p = 0; p < npass; ++p) {
        s_gemm<<<dim3(NTOK / 128, R / 128, BATCH), 256, 0, stream>>>(
            Qh, Ql, Gh, Gl, cmask, smask, laccp, Ph, Pl, p * R, R);
        const int nb = (R / 64) * (CIN / 64) * BATCH;   // % 8 == 0 for R>=128
        pv_gemm<<<nb, 256, 0, stream>>>(
            Hh, Hl, H2h, H2l, Ph, Pl, laccp, content, cstat, out, p * R, R);
    }
}

// Round 10
// 895.100 us; speedup vs baseline: 4.5310x; 2.1433x over previous
//
#include <hip/hip_runtime.h>
#include <math.h>

typedef unsigned short u16;
typedef __attribute__((ext_vector_type(8))) short short8;
typedef __attribute__((ext_vector_type(4))) float f32x4;

static constexpr int BATCH = 4;
static constexpr int CIN   = 256;
static constexpr int CKEY  = 448;
static constexpr int NTOK  = 4096;
static constexpr int KSEG  = 4;
static constexpr int KLEN  = NTOK / KSEG;   // 1024

// ---- bf16 helpers (round-to-nearest-even) ---------------------------------
__device__ __forceinline__ u16 f2bf(float x) {
    unsigned u = __float_as_uint(x);
    return (u16)((u + 0x7fffu + ((u >> 16) & 1u)) >> 16);
}
__device__ __forceinline__ float bf2f(u16 h) {
    return __uint_as_float(((unsigned)h) << 16);
}

// LDS layout: [rows][BK=32] bf16 panels as 16B slots (4/row), pair-interleaved
// XOR mapping -> 2-way conflicts (free, measured 0), bijective.  16B-slot idx.
__device__ __forceinline__ int lds16(int row, int s) {
    return ((row >> 1) << 3) + ((((row & 1) << 2) + s) ^ ((row >> 1) & 7));
}
// inverse: linear slot L -> (row, s).  unswz(lds16(r,s)) == (r,s)  (verified)
__device__ __forceinline__ void unswz(int L, int& row, int& s) {
    const int rp = L >> 3, xi = (L & 7) ^ (rp & 7);
    row = 2 * rp + (xi >> 2);
    s = xi & 3;
}
// async global->LDS 16B: per-lane global src, wave-uniform LDS base (+lane*16)
__device__ __forceinline__ void gl16(const u16* g, u16* l) {
    __builtin_amdgcn_global_load_lds(
        (const __attribute__((address_space(1))) unsigned int*)g,
        (__attribute__((address_space(3))) unsigned int*)l, 16, 0, 0);
}

// ---------------------------------------------------------------------------
// proj_nt_split: out[b][n][o] = sum_k X[b][k][n]*W[o][k] + bias[o], split bf16
// ---------------------------------------------------------------------------
template<int K>
__global__ __launch_bounds__(256)
void proj_nt_split(const float* __restrict__ X, const float* __restrict__ W,
                   const float* __restrict__ bias,
                   u16* __restrict__ outH, u16* __restrict__ outL, int O)
{
    const int n0 = blockIdx.x * 64;
    const int o0 = blockIdx.y * 64;
    const int b  = blockIdx.z;
    const int t  = threadIdx.x;
    const int tx = t & 15, ty = t >> 4;

    __shared__ float Xs[16][68];
    __shared__ float Wst[16][68];

    const float* Xb = X + (size_t)b * K * NTOK;
    float acc[4][4] = {};

    for (int kc = 0; kc < K; kc += 16) {
        {
            const int k = t >> 4, n4 = (t & 15) * 4;
            *(float4*)&Xs[k][n4] =
                *(const float4*)(Xb + (size_t)(kc + k) * NTOK + n0 + n4);
        }
        {
            const int o = t >> 2, k4 = (t & 3) * 4;
            const float4 v = *(const float4*)(W + (size_t)(o0 + o) * K + kc + k4);
            Wst[k4 + 0][o] = v.x; Wst[k4 + 1][o] = v.y;
            Wst[k4 + 2][o] = v.z; Wst[k4 + 3][o] = v.w;
        }
        __syncthreads();
        #pragma unroll
        for (int k = 0; k < 16; ++k) {
            float a[4];
            #pragma unroll
            for (int i = 0; i < 4; ++i) a[i] = Xs[k][4 * ty + i];
            const float4 bb = *(const float4*)&Wst[k][4 * tx];
            const float bv[4] = {bb.x, bb.y, bb.z, bb.w};
            #pragma unroll
            for (int i = 0; i < 4; ++i)
                #pragma unroll
                for (int j = 0; j < 4; ++j) acc[i][j] += a[i] * bv[j];
        }
        __syncthreads();
    }
    #pragma unroll
    for (int i = 0; i < 4; ++i) {
        const int n = n0 + 4 * ty + i;
        u16 h[4], l[4];
        #pragma unroll
        for (int j = 0; j < 4; ++j) {
            const float v = acc[i][j] + bias[o0 + 4 * tx + j];
            h[j] = f2bf(v);
            l[j] = f2bf(v - bf2f(h[j]));
        }
        const size_t oidx = ((size_t)b * NTOK + n) * O + o0 + 4 * tx;
        *(ushort4*)(outH + oidx) = make_ushort4(h[0], h[1], h[2], h[3]);
        *(ushort4*)(outL + oidx) = make_ushort4(l[0], l[1], l[2], l[3]);
    }
}

// ---------------------------------------------------------------------------
// proj_tn_split (for H): writes H (2-term) and H^2 (2-term), chan-major
// ---------------------------------------------------------------------------
template<int K>
__global__ __launch_bounds__(256)
void proj_tn_split(const float* __restrict__ X, const float* __restrict__ W,
                   const float* __restrict__ bias,
                   u16* __restrict__ Hh, u16* __restrict__ Hl,
                   u16* __restrict__ H2h, u16* __restrict__ H2l)
{
    const int m0 = blockIdx.x * 64;
    const int o0 = blockIdx.y * 64;
    const int b  = blockIdx.z;
    const int t  = threadIdx.x;
    const int tx = t & 15, ty = t >> 4;

    __shared__ float Wo[64][20];
    __shared__ float Xs[16][68];

    const float* Xb = X + (size_t)b * K * NTOK;
    float acc[4][4] = {};

    for (int kc = 0; kc < K; kc += 16) {
        {
            const int o = t >> 2, k4 = (t & 3) * 4;
            *(float4*)&Wo[o][k4] =
                *(const float4*)(W + (size_t)(o0 + o) * K + kc + k4);
        }
        {
            const int k = t >> 4, m4 = (t & 15) * 4;
            *(float4*)&Xs[k][m4] =
                *(const float4*)(Xb + (size_t)(kc + k) * NTOK + m0 + m4);
        }
        __syncthreads();
        #pragma unroll
        for (int k = 0; k < 16; ++k) {
            float a[4];
            #pragma unroll
            for (int i = 0; i < 4; ++i) a[i] = Wo[4 * ty + i][k];
            const float4 bb = *(const float4*)&Xs[k][4 * tx];
            const float bv[4] = {bb.x, bb.y, bb.z, bb.w};
            #pragma unroll
            for (int i = 0; i < 4; ++i)
                #pragma unroll
                for (int j = 0; j < 4; ++j) acc[i][j] += a[i] * bv[j];
        }
        __syncthreads();
    }
    #pragma unroll
    for (int i = 0; i < 4; ++i) {
        const int o = o0 + 4 * ty + i;
        const float bo = bias[o];
        u16 vh[4], vl[4], wh[4], wl[4];
        #pragma unroll
        for (int j = 0; j < 4; ++j) {
            const float v  = acc[i][j] + bo;
            const float v2 = v * v;
            vh[j] = f2bf(v);  vl[j] = f2bf(v  - bf2f(vh[j]));
            wh[j] = f2bf(v2); wl[j] = f2bf(v2 - bf2f(wh[j]));
        }
        const size_t oidx = ((size_t)b * CIN + o) * NTOK + m0 + 4 * tx;
        *(ushort4*)(Hh  + oidx) = make_ushort4(vh[0], vh[1], vh[2], vh[3]);
        *(ushort4*)(Hl  + oidx) = make_ushort4(vl[0], vl[1], vl[2], vl[3]);
        *(ushort4*)(H2h + oidx) = make_ushort4(wh[0], wh[1], wh[2], wh[3]);
        *(ushort4*)(H2l + oidx) = make_ushort4(wl[0], wl[1], wl[2], wl[3]);
    }
}

// ---------------------------------------------------------------------------
// content stats: per (b,c) mean + rstd (unbiased) over 4096 tokens
// ---------------------------------------------------------------------------
__global__ __launch_bounds__(256)
void content_stats(const float* __restrict__ content, float* __restrict__ stat)
{
    const int bc = blockIdx.x;
    const float* p = content + (size_t)bc * NTOK;
    float s = 0.f, s2 = 0.f;
    for (int i = threadIdx.x; i < NTOK; i += 256) {
        const float x = p[i];
        s += x; s2 += x * x;
    }
    #pragma unroll
    for (int off = 32; off; off >>= 1) {
        s  += __shfl_down(s, off);
        s2 += __shfl_down(s2, off);
    }
    __shared__ float rs[4], rs2[4];
    const int w = threadIdx.x >> 6;
    if ((threadIdx.x & 63) == 0) { rs[w] = s; rs2[w] = s2; }
    __syncthreads();
    if (threadIdx.x == 0) {
        const float S  = rs[0] + rs[1] + rs[2] + rs[3];
        const float S2 = rs2[0] + rs2[1] + rs2[2] + rs2[3];
        const float mean = S / (float)NTOK;
        const float var  = (S2 - S * mean) / (float)(NTOK - 1);
        stat[bc] = mean;
        stat[BATCH * CIN + bc] = rsqrtf(var + 1e-5f);
    }
}

__global__ void zero_f32(float* p, int n)
{
    const int i = blockIdx.x * 256 + threadIdx.x;
    if (i < n) p[i] = 0.f;
}

// ---------------------------------------------------------------------------
// s_gemm: S = Q·G^T (split-bf16 3-term) -> p = mask?0:exp(S) -> Ph/Pl,
// row sums into lacc (atomics).  Tile 128x128, BK=32, 4 waves.
// m97-style staging: global_load_lds(16B), linear LDS dest, pre-unswizzled
// per-lane global source (content identical to lds16 layout; reads unchanged).
// grid: (NTOK/128 m-tiles, R/128 n-tiles, BATCH)
// ---------------------------------------------------------------------------
__global__ __launch_bounds__(256)
void s_gemm(const u16* __restrict__ Qh, const u16* __restrict__ Ql,
            const u16* __restrict__ Gh, const u16* __restrict__ Gl,
            const int* __restrict__ cmask, const int* __restrict__ smask,
            float* __restrict__ lacc,
            u16* __restrict__ Ph, u16* __restrict__ Pl, int n_base, int Rrows)
{
    const int m0 = blockIdx.x * 128;
    const int nl_base = blockIdx.y * 128;
    const int n0 = n_base + nl_base;
    const int b  = blockIdx.z;
    const int t  = threadIdx.x;
    const int lane = t & 63, wid = t >> 6;
    const int g = lane >> 4, lr = lane & 15;
    const int wrow = (wid & 1) * 64;
    const int wcol = (wid >> 1) * 64;

    __shared__ __align__(16) u16 LAh[4096], LAl[4096], LBh[4096], LBl[4096];

    const size_t qoff = ((size_t)b * NTOK + n0) * CKEY;
    const size_t goff = ((size_t)b * NTOK + m0) * CKEY;

    // staging geometry: 512 slots/panel, 2 issues/thread; slot L = i*256 + t
    size_t aoff[2], boff[2];
    int lb[2];
    #pragma unroll
    for (int i = 0; i < 2; ++i) {
        int row, s;
        unswz(i * 256 + t, row, s);
        aoff[i] = qoff + (size_t)row * CKEY + s * 8;
        boff[i] = goff + (size_t)row * CKEY + s * 8;
        lb[i] = (i * 256 + wid * 64) * 8;   // u16 index of wave-uniform base
    }

    const f32x4 zf = {0.f, 0.f, 0.f, 0.f};
    f32x4 acc[4][4];
    #pragma unroll
    for (int i = 0; i < 4; ++i)
        #pragma unroll
        for (int j = 0; j < 4; ++j) acc[i][j] = zf;

    for (int kc = 0; kc < CKEY; kc += 32) {
        gl16(Qh + aoff[0] + kc, LAh + lb[0]);
        gl16(Qh + aoff[1] + kc, LAh + lb[1]);
        gl16(Ql + aoff[0] + kc, LAl + lb[0]);
        gl16(Ql + aoff[1] + kc, LAl + lb[1]);
        gl16(Gh + boff[0] + kc, LBh + lb[0]);
        gl16(Gh + boff[1] + kc, LBh + lb[1]);
        gl16(Gl + boff[0] + kc, LBl + lb[0]);
        gl16(Gl + boff[1] + kc, LBl + lb[1]);
        __syncthreads();   // drains vmcnt -> staged data visible

        short8 bh[4], bl[4];
        #pragma unroll
        for (int tc = 0; tc < 4; ++tc) {
            const int br = wcol + tc * 16 + lr;
            bh[tc] = *(const short8*)&LBh[lds16(br, g) * 8];
            bl[tc] = *(const short8*)&LBl[lds16(br, g) * 8];
        }
        #pragma unroll
        for (int tr = 0; tr < 4; ++tr) {
            const int ar = wrow + tr * 16 + lr;
            const short8 ah = *(const short8*)&LAh[lds16(ar, g) * 8];
            const short8 al = *(const short8*)&LAl[lds16(ar, g) * 8];
            #pragma unroll
            for (int tc = 0; tc < 4; ++tc) {
                acc[tr][tc] = __builtin_amdgcn_mfma_f32_16x16x32_bf16(ah, bh[tc], acc[tr][tc], 0, 0, 0);
                acc[tr][tc] = __builtin_amdgcn_mfma_f32_16x16x32_bf16(ah, bl[tc], acc[tr][tc], 0, 0, 0);
                acc[tr][tc] = __builtin_amdgcn_mfma_f32_16x16x32_bf16(al, bh[tc], acc[tr][tc], 0, 0, 0);
            }
        }
        __syncthreads();   // all reads done before next chunk overwrites
    }

    // epilogue: mask + exp + split-store + row sums
    int smv[4];
    #pragma unroll
    for (int tc = 0; tc < 4; ++tc)
        smv[tc] = smask[b * NTOK + m0 + wcol + tc * 16 + lr];

    #pragma unroll
    for (int tr = 0; tr < 4; ++tr) {
        int cmr[4];
        #pragma unroll
        for (int r = 0; r < 4; ++r)
            cmr[r] = cmask[b * NTOK + n0 + wrow + tr * 16 + 4 * g + r];
        float rowsum[4] = {0.f, 0.f, 0.f, 0.f};
        #pragma unroll
        for (int tc = 0; tc < 4; ++tc) {
            #pragma unroll
            for (int r = 0; r < 4; ++r) {
                const float p = (cmr[r] && smv[tc] == 0) ? 0.f
                                                         : __expf(acc[tr][tc][r]);
                rowsum[r] += p;
                const u16 hi = f2bf(p);
                const u16 lo = f2bf(p - bf2f(hi));
                const int nloc = nl_base + wrow + tr * 16 + 4 * g + r;
                const int m = m0 + wcol + tc * 16 + lr;
                const size_t pidx = ((size_t)b * Rrows + nloc) * NTOK + m;
                Ph[pidx] = hi; Pl[pidx] = lo;
            }
        }
        #pragma unroll
        for (int r = 0; r < 4; ++r) {
            float v = rowsum[r];
            v += __shfl_xor(v, 1); v += __shfl_xor(v, 2);
            v += __shfl_xor(v, 4); v += __shfl_xor(v, 8);
            if (lr == 0)
                atomicAdd(&lacc[b * NTOK + n0 + wrow + tr * 16 + 4 * g + r], v);
        }
    }
}

// ---------------------------------------------------------------------------
// pv_partial: partial mean/m2 over one K segment (KLEN=1024), 3-term MFMA.
// Tile 64c x 64n, 4 waves (each 32c x 32n).  Writes f32 partials
// [seg][b][c][n] (each element once; no atomics).  m97-style staging.
// 1-D grid with bijective XCD swizzle, c fastest (P panel L2 sharing).
// ---------------------------------------------------------------------------
__global__ __launch_bounds__(256)
void pv_partial(const u16* __restrict__ Hh, const u16* __restrict__ Hl,
                const u16* __restrict__ H2h, const u16* __restrict__ H2l,
                const u16* __restrict__ Ph, const u16* __restrict__ Pl,
                float* __restrict__ pM, float* __restrict__ pS, int Rrows)
{
    const int nb = gridDim.x;
    const int swz = (blockIdx.x & 7) * (nb >> 3) + (blockIdx.x >> 3);
    const int ntiles = Rrows >> 6;
    const int c0 = (swz & 3) * 64;
    int r2 = swz >> 2;
    const int n_t = r2 % ntiles;
    r2 /= ntiles;
    const int b   = r2 & 3;
    const int seg = r2 >> 2;
    const int nl0 = n_t * 64;

    const int t = threadIdx.x, lane = t & 63, wid = t >> 6;
    const int g = lane >> 4, lr = lane & 15;
    const int wrow = (wid & 1) * 32;            // c side
    const int wcol = (wid >> 1) * 32;           // n side

    __shared__ __align__(16) u16 LHh[2048], LHl[2048], L2h[2048], L2l[2048];
    __shared__ __align__(16) u16 LPh[2048], LPl[2048];

    const size_t hoff = ((size_t)b * CIN + c0) * NTOK;
    const size_t poff = ((size_t)b * Rrows + nl0) * NTOK;

    // staging geometry: 256 slots/panel, 1 issue/thread; slot L = t
    int srow, ss;
    unswz(t, srow, ss);
    const size_t offA = (size_t)srow * NTOK + ss * 8 + (size_t)seg * KLEN;
    const int lb = wid * 64 * 8;

    const f32x4 zf = {0.f, 0.f, 0.f, 0.f};
    f32x4 accM[2][2], accS[2][2];
    #pragma unroll
    for (int i = 0; i < 2; ++i)
        #pragma unroll
        for (int j = 0; j < 2; ++j) { accM[i][j] = zf; accS[i][j] = zf; }

    for (int kc = 0; kc < KLEN; kc += 32) {
        gl16(Hh  + hoff + offA + kc, LHh + lb);
        gl16(Hl  + hoff + offA + kc, LHl + lb);
        gl16(H2h + hoff + offA + kc, L2h + lb);
        gl16(H2l + hoff + offA + kc, L2l + lb);
        gl16(Ph  + poff + offA + kc, LPh + lb);
        gl16(Pl  + poff + offA + kc, LPl + lb);
        __syncthreads();

        short8 pbh[2], pbl[2];
        #pragma unroll
        for (int tc = 0; tc < 2; ++tc) {
            const int pr = wcol + tc * 16 + lr;
            pbh[tc] = *(const short8*)&LPh[lds16(pr, g) * 8];
            pbl[tc] = *(const short8*)&LPl[lds16(pr, g) * 8];
        }
        #pragma unroll
        for (int tr = 0; tr < 2; ++tr) {
            const int cr = wrow + tr * 16 + lr;
            const short8 hh  = *(const short8*)&LHh[lds16(cr, g) * 8];
            const short8 hl  = *(const short8*)&LHl[lds16(cr, g) * 8];
            const short8 q2h = *(const short8*)&L2h[lds16(cr, g) * 8];
            const short8 q2l = *(const short8*)&L2l[lds16(cr, g) * 8];
            #pragma unroll
            for (int tc = 0; tc < 2; ++tc) {
                accM[tr][tc] = __builtin_amdgcn_mfma_f32_16x16x32_bf16(hh,  pbh[tc], accM[tr][tc], 0, 0, 0);
                accM[tr][tc] = __builtin_amdgcn_mfma_f32_16x16x32_bf16(hh,  pbl[tc], accM[tr][tc], 0, 0, 0);
                accM[tr][tc] = __builtin_amdgcn_mfma_f32_16x16x32_bf16(hl,  pbh[tc], accM[tr][tc], 0, 0, 0);
                accS[tr][tc] = __builtin_amdgcn_mfma_f32_16x16x32_bf16(q2h, pbh[tc], accS[tr][tc], 0, 0, 0);
                accS[tr][tc] = __builtin_amdgcn_mfma_f32_16x16x32_bf16(q2h, pbl[tc], accS[tr][tc], 0, 0, 0);
                accS[tr][tc] = __builtin_amdgcn_mfma_f32_16x16x32_bf16(q2l, pbh[tc], accS[tr][tc], 0, 0, 0);
            }
        }
        __syncthreads();
    }

    // store partials [seg][b][c][n-local], coalesced over n (lr)
    #pragma unroll
    for (int tc = 0; tc < 2; ++tc) {
        const int n = nl0 + wcol + tc * 16 + lr;
        #pragma unroll
        for (int tr = 0; tr < 2; ++tr) {
            #pragma unroll
            for (int r = 0; r < 4; ++r) {
                const int c = c0 + wrow + tr * 16 + 4 * g + r;
                const size_t o = (((size_t)seg * BATCH + b) * CIN + c) * Rrows + n;
                pM[o] = accM[tr][tc][r];
                pS[o] = accS[tr][tc][r];
            }
        }
    }
}

// ---------------------------------------------------------------------------
// pv_epilogue: sum KSEG partials, /lacc, std, AdaAttN transform, store out.
// ---------------------------------------------------------------------------
__global__ __launch_bounds__(256)
void pv_epilogue(const float* __restrict__ pM, const float* __restrict__ pS,
                 const float* __restrict__ lacc, const float* __restrict__ content,
                 const float* __restrict__ cstat, float* __restrict__ out,
                 int n_base, int Rrows)
{
    const int nq = Rrows >> 2;
    const int i = blockIdx.x * 256 + threadIdx.x;
    if (i >= BATCH * CIN * nq) return;
    const int n4 = (i % nq) << 2;
    const int bc = i / nq;
    const int b = bc / CIN;

    f32x4 m = {0.f, 0.f, 0.f, 0.f}, s2 = {0.f, 0.f, 0.f, 0.f};
    #pragma unroll
    for (int seg = 0; seg < KSEG; ++seg) {
        const size_t o = ((size_t)seg * BATCH * CIN + bc) * Rrows + n4;
        m  += *(const f32x4*)(pM + o);
        s2 += *(const f32x4*)(pS + o);
    }
    const f32x4 la = *(const f32x4*)(lacc + (size_t)b * NTOK + n_base + n4);
    const size_t oidx = (size_t)bc * NTOK + n_base + n4;
    const f32x4 cont = *(const f32x4*)(content + oidx);
    const float cm = cstat[bc];
    const float cr = cstat[BATCH * CIN + bc];
    f32x4 o4;
    #pragma unroll
    for (int j = 0; j < 4; ++j) {
        const float rl = 1.f / fmaxf(la[j], 1e-35f);
        const float mu = m[j] * rl;
        const float m2 = s2[j] * rl;
        const float sd = sqrtf(fmaxf(m2 - mu * mu, 0.f));
        o4[j] = sd * ((cont[j] - cm) * cr) + mu;
    }
    *(f32x4*)(out + oidx) = o4;
}

// ---------------------------------------------------------------------------
extern "C" void kernel_launch(void* const* d_in, const int* in_sizes, int n_in,
                              void* d_out, int out_size, void* d_ws, size_t ws_size,
                              hipStream_t stream)
{
    const float* content = (const float*)d_in[0];
    const float* style   = (const float*)d_in[1];
    const float* ckey    = (const float*)d_in[2];
    const float* skey    = (const float*)d_in[3];
    const int*   cmask   = (const int*)d_in[4];
    const int*   smask   = (const int*)d_in[5];
    const float* Wf      = (const float*)d_in[6];
    const float* bf      = (const float*)d_in[7];
    const float* Wg      = (const float*)d_in[8];
    const float* bg      = (const float*)d_in[9];
    const float* Wh      = (const float*)d_in[10];
    const float* bh      = (const float*)d_in[11];
    float* out = (float*)d_out;

    const size_t SZQ = (size_t)BATCH * NTOK * CKEY;   // elements (u16)
    const size_t SZH = (size_t)BATCH * CIN * NTOK;

    char* cur = (char*)d_ws;
    auto take = [&](size_t bytes) { char* r = cur; cur += bytes; return r; };

    u16* Qh  = (u16*)take(SZQ * 2);
    u16* Ql  = (u16*)take(SZQ * 2);
    u16* Gh  = (u16*)take(SZQ * 2);
    u16* Gl  = (u16*)take(SZQ * 2);
    u16* Hh  = (u16*)take(SZH * 2);
    u16* Hl  = (u16*)take(SZH * 2);
    u16* H2h = (u16*)take(SZH * 2);
    u16* H2l = (u16*)take(SZH * 2);
    float* laccp = (float*)take((size_t)BATCH * NTOK * 4);
    float* cstat = (float*)take((size_t)2 * BATCH * CIN * 4);

    // per-pass: P (2-term bf16) = 65536*R bytes; partials = 32768*R bytes
    const size_t rem = ws_size - (size_t)(cur - (char*)d_ws);
    int R = 1024;
    while (R > 128 && (size_t)98304 * R > rem) R >>= 1;
    float* pM = (float*)take((size_t)KSEG * BATCH * CIN * R * 4);
    float* pS = (float*)take((size_t)KSEG * BATCH * CIN * R * 4);
    u16* Ph = (u16*)cur;
    u16* Pl = Ph + (size_t)BATCH * R * NTOK;

    proj_nt_split<CKEY><<<dim3(NTOK / 64, CKEY / 64, BATCH), 256, 0, stream>>>(
        ckey, Wf, bf, Qh, Ql, CKEY);
    proj_nt_split<CKEY><<<dim3(NTOK / 64, CKEY / 64, BATCH), 256, 0, stream>>>(
        skey, Wg, bg, Gh, Gl, CKEY);
    proj_tn_split<CIN><<<dim3(NTOK / 64, CIN / 64, BATCH), 256, 0, stream>>>(
        style, Wh, bh, Hh, Hl, H2h, H2l);
    content_stats<<<BATCH * CIN, 256, 0, stream>>>(content, cstat);
    zero_f32<<<(BATCH * NTOK + 255) / 256, 256, 0, stream>>>(laccp, BATCH * NTOK);

    const int npass = NTOK / R;
    for (int p = 0; p < npass; ++p) {
        s_gemm<<<dim3(NTOK / 128, R / 128, BATCH), 256, 0, stream>>>(
            Qh, Ql, Gh, Gl, cmask, smask, laccp, Ph, Pl, p * R, R);
        const int nb = (R / 64) * (CIN / 64) * BATCH * KSEG;   // % 8 == 0
        pv_partial<<<nb, 256, 0, stream>>>(
            Hh, Hl, H2h, H2l, Ph, Pl, pM, pS, R);
        pv_epilogue<<<(BATCH * CIN * (R / 4) + 255) / 256, 256, 0, stream>>>(
            pM, pS, laccp, content, cstat, out, p * R, R);
    }
}